// Round 2
// baseline (25093.829 us; speedup 1.0000x reference)
//
#include <hip/hip_runtime.h>
#include <hip/hip_bf16.h>

#define T_LEN 2048
#define G_N   24
#define V_N   2048
#define K_N   512
#define NCLUSTER 48   // G_N * 2 directions
#define WG_PER_CL 4
#define NBLK (NCLUSTER * WG_PER_CL)   // 192

// ---------------- workspace layout (bytes) ----------------
#define FLAGS_OFF  0
#define TOK_OFF    4096
#define ROWS_OFF   16384
#define HBUF_OFF   262144
#define P_OFF      524288

// ---- phase 0: recover tokens from one-hot rows (exactly one 1.0 per row) ----
__global__ void tok_kernel(const float* __restrict__ seq, int* __restrict__ tokens) {
    int wid  = (blockIdx.x * blockDim.x + threadIdx.x) >> 6;   // one wave per row t
    int lane = threadIdx.x & 63;
    if (wid >= T_LEN) return;
    const float* row = seq + (size_t)wid * V_N;
    for (int i = lane; i < V_N; i += 64) {
        if (row[i] > 0.5f) tokens[wid] = i;   // exactly one lane hits: race-free
    }
}

// ---- phase 1: rows[g][t] = perms[g][token[t]] ----
__global__ void rows_kernel(const int* __restrict__ tokens, const int* __restrict__ perms,
                            int* __restrict__ rows) {
    int idx = blockIdx.x * blockDim.x + threadIdx.x;   // g*T + t
    if (idx >= G_N * T_LEN) return;
    int g = idx / T_LEN, t = idx - g * T_LEN;
    rows[idx] = perms[g * V_N + tokens[t]];
}

// ---- phase 2: P = W_e @ Wx + b  (2048x512 @ 512x512, f32 vector GEMM) ----
__global__ __launch_bounds__(256) void pgemm_kernel(const float* __restrict__ We,
                                                    const float* __restrict__ Wx,
                                                    const float* __restrict__ b,
                                                    float* __restrict__ P) {
    __shared__ float As[16][72];   // [k][v], padded
    __shared__ float Bs[16][68];   // [k][j], padded (68 keeps float4 alignment)
    int tid = threadIdx.x;
    int bx = blockIdx.x & 7;        // j tile (K_N/64 = 8)
    int by = blockIdx.x >> 3;       // v tile (V_N/64 = 32)
    int tx = tid & 15, ty = tid >> 4;
    int v0 = by * 64, j0 = bx * 64;
    float acc[4][4] = {};
    for (int k0 = 0; k0 < K_N; k0 += 16) {
        int ar = tid >> 2;            // 0..63
        int ac = (tid & 3) << 2;      // 0,4,8,12
        float4 av = *(const float4*)(We + (size_t)(v0 + ar) * K_N + k0 + ac);
        As[ac + 0][ar] = av.x; As[ac + 1][ar] = av.y;
        As[ac + 2][ar] = av.z; As[ac + 3][ar] = av.w;
        int br = tid >> 4;            // 0..15
        int bc = (tid & 15) << 2;     // 0..60
        float4 bv = *(const float4*)(Wx + (size_t)(k0 + br) * K_N + j0 + bc);
        *(float4*)&Bs[br][bc] = bv;
        __syncthreads();
#pragma unroll
        for (int kk = 0; kk < 16; kk++) {
            float a0 = As[kk][ty * 4 + 0], a1 = As[kk][ty * 4 + 1];
            float a2 = As[kk][ty * 4 + 2], a3 = As[kk][ty * 4 + 3];
            float4 bb = *(const float4*)&Bs[kk][tx * 4];
            acc[0][0] += a0 * bb.x; acc[0][1] += a0 * bb.y; acc[0][2] += a0 * bb.z; acc[0][3] += a0 * bb.w;
            acc[1][0] += a1 * bb.x; acc[1][1] += a1 * bb.y; acc[1][2] += a1 * bb.z; acc[1][3] += a1 * bb.w;
            acc[2][0] += a2 * bb.x; acc[2][1] += a2 * bb.y; acc[2][2] += a2 * bb.z; acc[2][3] += a2 * bb.w;
            acc[3][0] += a3 * bb.x; acc[3][1] += a3 * bb.y; acc[3][2] += a3 * bb.z; acc[3][3] += a3 * bb.w;
        }
        __syncthreads();
    }
    float4 bb = *(const float4*)(b + j0 + tx * 4);
#pragma unroll
    for (int i = 0; i < 4; i++) {
        float4 r;
        r.x = acc[i][0] + bb.x; r.y = acc[i][1] + bb.y;
        r.z = acc[i][2] + bb.z; r.w = acc[i][3] + bb.w;
        *(float4*)(P + (size_t)(v0 + ty * 4 + i) * K_N + j0 + tx * 4) = r;
    }
}

// ---- phase 3: persistent bidirectional RNN ----
// 48 clusters (g, dir) x 4 WGs x 512 threads. Each WG owns 128 columns of Wh
// in VGPRs (128 f32/thread). Wave w: kq = w&3 (k-range 128*kq..+128),
// ch = w>>2 (column half); lane -> col = c0 + 64*ch + lane.
// h broadcast via LDS (all-lane-same-address reads); cross-wave reduce via LDS;
// 4-WG h exchange through LLC with double-buffered h_buf + monotone flags.
// Sync: release store of my flag; acquire loads in the spin (hb stores of the
// peer happen-before its flag store, so after observing flag>=target with an
// acquire load, reading its hb slice is safe).
__global__ __launch_bounds__(512, 2) void rnn_kernel(
    const float* __restrict__ P, const float* __restrict__ Wh,
    const int* __restrict__ rows, float* __restrict__ h_buf,
    int* __restrict__ flags, float* __restrict__ out) {

    __shared__ __align__(16) float lds_h[512];
    __shared__ float partial[512];

    const int bid = blockIdx.x;
    const int cluster = bid >> 2;          // 0..47
    const int wgc = bid & 3;               // 0..3
    const int g = cluster % G_N;
    const int dir = cluster / G_N;         // 0 fwd, 1 bwd
    const int tid = threadIdx.x;
    const int w = tid >> 6, lane = tid & 63;
    const int kq = w & 3, ch = w >> 2;
    const int c0 = wgc << 7;                     // column base, 128 per WG
    const int col = c0 + (ch << 6) + lane;       // this thread's Wh column
    const int kbase = kq << 7;                   // this thread's k range base

    // Wh slice -> registers (one-time, L2-served)
    float Wreg[128];
#pragma unroll
    for (int i = 0; i < 128; i++)
        Wreg[i] = Wh[(size_t)(kbase + i) * K_N + col];

    lds_h[tid] = 0.f;                            // h_0 = 0

    const int* myrows = rows + g * T_LEN;
    int* myflags = flags + cluster * 4;
    float* hb0 = h_buf + (size_t)cluster * 512;
    float* hb1 = h_buf + (size_t)NCLUSTER * 512 + (size_t)cluster * 512;

    __syncthreads();

    // prefetch x for s = 0
    const int colr = c0 + (tid & 127);
    float xv = 0.f;
    if (tid < 128) {
        int t0 = (dir == 0) ? 0 : (T_LEN - 2);
        xv = P[(size_t)myrows[t0] * K_N + colr];
    }

    for (int s = 0; s < T_LEN; s++) {
        // partial dot over my 128 k's for my column (LDS broadcast reads)
        float a0 = 0.f, a1 = 0.f, a2 = 0.f, a3 = 0.f;
#pragma unroll
        for (int i = 0; i < 128; i += 4) {
            float4 hv = *(const float4*)&lds_h[kbase + i];   // uniform addr -> broadcast
            a0 += hv.x * Wreg[i + 0];
            a1 += hv.y * Wreg[i + 1];
            a2 += hv.z * Wreg[i + 2];
            a3 += hv.w * Wreg[i + 3];
        }
        partial[tid] = (a0 + a1) + (a2 + a3);
        __syncthreads();                                     // A

        if (tid < 128) {
            int chh = tid >> 6, l = tid & 63;
            float sum = partial[(chh * 4 + 0) * 64 + l] + partial[(chh * 4 + 1) * 64 + l]
                      + partial[(chh * 4 + 2) * 64 + l] + partial[(chh * 4 + 3) * 64 + l];
            float z = xv + sum;
            z = fminf(15.f, fmaxf(-15.f, z));
            float e = __expf(2.f * z);
            float h1 = 1.f - 2.f / (e + 1.f);                // tanh(z)

            int tphys = (dir == 0) ? s : ((s == T_LEN - 1) ? (T_LEN - 1) : (T_LEN - 2 - s));
            out[(size_t)tphys * (G_N * 1024) + g * 1024 + dir * 512 + colr] = h1;
            if (s == T_LEN - 1)
                out[(size_t)T_LEN * (G_N * 1024) + g * 1024 + dir * 512 + colr] = h1;

            float* hb = (s & 1) ? hb1 : hb0;
            hb[colr] = h1;                                   // my 128-slice of h_{s+1}
        }
        if (s == T_LEN - 1) break;
        __syncthreads();                                     // B: drains stores (vmcnt)

        if (tid == 0)
            __hip_atomic_store(&myflags[wgc], s + 1, __ATOMIC_RELEASE, __HIP_MEMORY_SCOPE_AGENT);

        // prefetch next x while waiting (P/rows immutable -> stale reads fine)
        if (tid < 128) {
            int sn = s + 1;
            int tn = (dir == 0) ? sn : ((sn == T_LEN - 1) ? (T_LEN - 1) : (T_LEN - 2 - sn));
            xv = P[(size_t)myrows[tn] * K_N + colr];
        }

        if (tid == 0) {
            const int target = s + 1;
            while (true) {
                int f0 = __hip_atomic_load(&myflags[0], __ATOMIC_ACQUIRE, __HIP_MEMORY_SCOPE_AGENT);
                int f1 = __hip_atomic_load(&myflags[1], __ATOMIC_ACQUIRE, __HIP_MEMORY_SCOPE_AGENT);
                int f2 = __hip_atomic_load(&myflags[2], __ATOMIC_ACQUIRE, __HIP_MEMORY_SCOPE_AGENT);
                int f3 = __hip_atomic_load(&myflags[3], __ATOMIC_ACQUIRE, __HIP_MEMORY_SCOPE_AGENT);
                if (f0 >= target && f1 >= target && f2 >= target && f3 >= target) break;
            }
        }
        __syncthreads();                                     // C
        {
            const float* hb = (s & 1) ? hb1 : hb0;
            lds_h[tid] = hb[tid];                            // full h_{s+1} -> LDS
        }
        __syncthreads();                                     // D
    }
}

extern "C" void kernel_launch(void* const* d_in, const int* in_sizes, int n_in,
                              void* d_out, int out_size, void* d_ws, size_t ws_size,
                              hipStream_t stream) {
    const float* seq   = (const float*)d_in[0];
    const int*   perms = (const int*)d_in[1];
    const float* We    = (const float*)d_in[2];
    const float* Wx    = (const float*)d_in[3];
    const float* Wh    = (const float*)d_in[4];
    const float* b     = (const float*)d_in[5];
    float* out = (float*)d_out;
    char* ws = (char*)d_ws;

    int*   flags  = (int*)(ws + FLAGS_OFF);
    int*   tokens = (int*)(ws + TOK_OFF);
    int*   rows   = (int*)(ws + ROWS_OFF);
    float* hbuf   = (float*)(ws + HBUF_OFF);
    float* P      = (float*)(ws + P_OFF);

    (void)hipMemsetAsync(flags, 0, NCLUSTER * 4 * sizeof(int), stream);
    tok_kernel<<<512, 256, 0, stream>>>(seq, tokens);
    rows_kernel<<<(G_N * T_LEN + 255) / 256, 256, 0, stream>>>(tokens, perms, rows);
    pgemm_kernel<<<256, 256, 0, stream>>>(We, Wx, b, P);
    rnn_kernel<<<NBLK, 512, 0, stream>>>(P, Wh, rows, hbuf, flags, out);
}

// Round 3
// 8551.874 us; speedup vs baseline: 2.9343x; 2.9343x over previous
//
#include <hip/hip_runtime.h>
#include <hip/hip_bf16.h>

#define T_LEN 2048
#define G_N   24
#define V_N   2048
#define K_N   512
#define NCLUSTER 48   // G_N * 2 directions
#define WG_PER_CL 4
#define NBLK (NCLUSTER * WG_PER_CL)   // 192

// ---------------- workspace layout (bytes) ----------------
#define FLAGS_OFF  0
#define TOK_OFF    4096
#define ROWS_OFF   16384
#define HBUF_OFF   262144
#define P_OFF      524288

#define LOAD_RLX(p)     __hip_atomic_load((p), __ATOMIC_RELAXED, __HIP_MEMORY_SCOPE_AGENT)
#define STORE_RLX(p, v) __hip_atomic_store((p), (v), __ATOMIC_RELAXED, __HIP_MEMORY_SCOPE_AGENT)

// ---- phase 0: recover tokens from one-hot rows (exactly one 1.0 per row) ----
__global__ void tok_kernel(const float* __restrict__ seq, int* __restrict__ tokens) {
    int wid  = (blockIdx.x * blockDim.x + threadIdx.x) >> 6;   // one wave per row t
    int lane = threadIdx.x & 63;
    if (wid >= T_LEN) return;
    const float* row = seq + (size_t)wid * V_N;
    for (int i = lane; i < V_N; i += 64) {
        if (row[i] > 0.5f) tokens[wid] = i;   // exactly one lane hits: race-free
    }
}

// ---- phase 1: rows[g][t] = perms[g][token[t]] ----
__global__ void rows_kernel(const int* __restrict__ tokens, const int* __restrict__ perms,
                            int* __restrict__ rows) {
    int idx = blockIdx.x * blockDim.x + threadIdx.x;   // g*T + t
    if (idx >= G_N * T_LEN) return;
    int g = idx / T_LEN, t = idx - g * T_LEN;
    rows[idx] = perms[g * V_N + tokens[t]];
}

// ---- phase 2: P = W_e @ Wx + b  (2048x512 @ 512x512, f32 vector GEMM) ----
__global__ __launch_bounds__(256) void pgemm_kernel(const float* __restrict__ We,
                                                    const float* __restrict__ Wx,
                                                    const float* __restrict__ b,
                                                    float* __restrict__ P) {
    __shared__ float As[16][72];   // [k][v], padded
    __shared__ float Bs[16][68];   // [k][j], padded (68 keeps float4 alignment)
    int tid = threadIdx.x;
    int bx = blockIdx.x & 7;        // j tile (K_N/64 = 8)
    int by = blockIdx.x >> 3;       // v tile (V_N/64 = 32)
    int tx = tid & 15, ty = tid >> 4;
    int v0 = by * 64, j0 = bx * 64;
    float acc[4][4] = {};
    for (int k0 = 0; k0 < K_N; k0 += 16) {
        int ar = tid >> 2;            // 0..63
        int ac = (tid & 3) << 2;      // 0,4,8,12
        float4 av = *(const float4*)(We + (size_t)(v0 + ar) * K_N + k0 + ac);
        As[ac + 0][ar] = av.x; As[ac + 1][ar] = av.y;
        As[ac + 2][ar] = av.z; As[ac + 3][ar] = av.w;
        int br = tid >> 4;            // 0..15
        int bc = (tid & 15) << 2;     // 0..60
        float4 bv = *(const float4*)(Wx + (size_t)(k0 + br) * K_N + j0 + bc);
        *(float4*)&Bs[br][bc] = bv;
        __syncthreads();
#pragma unroll
        for (int kk = 0; kk < 16; kk++) {
            float a0 = As[kk][ty * 4 + 0], a1 = As[kk][ty * 4 + 1];
            float a2 = As[kk][ty * 4 + 2], a3 = As[kk][ty * 4 + 3];
            float4 bb = *(const float4*)&Bs[kk][tx * 4];
            acc[0][0] += a0 * bb.x; acc[0][1] += a0 * bb.y; acc[0][2] += a0 * bb.z; acc[0][3] += a0 * bb.w;
            acc[1][0] += a1 * bb.x; acc[1][1] += a1 * bb.y; acc[1][2] += a1 * bb.z; acc[1][3] += a1 * bb.w;
            acc[2][0] += a2 * bb.x; acc[2][1] += a2 * bb.y; acc[2][2] += a2 * bb.z; acc[2][3] += a2 * bb.w;
            acc[3][0] += a3 * bb.x; acc[3][1] += a3 * bb.y; acc[3][2] += a3 * bb.z; acc[3][3] += a3 * bb.w;
        }
        __syncthreads();
    }
    float4 bb = *(const float4*)(b + j0 + tx * 4);
#pragma unroll
    for (int i = 0; i < 4; i++) {
        float4 r;
        r.x = acc[i][0] + bb.x; r.y = acc[i][1] + bb.y;
        r.z = acc[i][2] + bb.z; r.w = acc[i][3] + bb.w;
        *(float4*)(P + (size_t)(v0 + ty * 4 + i) * K_N + j0 + tx * 4) = r;
    }
}

// ---- phase 3: persistent bidirectional RNN ----
// 48 clusters (g, dir) x 4 WGs x 512 threads. Each WG owns 128 columns of Wh
// in registers. Per step: LDS-broadcast h, partial dots, LDS reduce, tanh,
// exchange 128-slices of h through the LLC.
// Sync design (the R2->R3 fix): h_buf + flags are accessed ONLY via relaxed
// agent-scope atomics -> sc1 ops that bypass L1/L2 and hit the LLC coherence
// point directly. No buffer_inv / no L2 writeback in the per-step path.
// out uses nontemporal stores so the L2 stays clean (release flag store's
// writeback is then free). Flag store is RELEASE (orders after h stores).
__global__ __launch_bounds__(512, 2) void rnn_kernel(
    const float* __restrict__ P, const float* __restrict__ Wh,
    const int* __restrict__ rows, float* __restrict__ h_buf,
    int* __restrict__ flags, float* __restrict__ out) {

    __shared__ __align__(16) float lds_h[512];
    __shared__ float partial[512];

    const int bid = blockIdx.x;
    const int cluster = bid >> 2;          // 0..47
    const int wgc = bid & 3;               // 0..3
    const int g = cluster % G_N;
    const int dir = cluster / G_N;         // 0 fwd, 1 bwd
    const int tid = threadIdx.x;
    const int w = tid >> 6, lane = tid & 63;
    const int kq = w & 3, ch = w >> 2;
    const int c0 = wgc << 7;                     // column base, 128 per WG
    const int col = c0 + (ch << 6) + lane;       // this thread's Wh column
    const int kbase = kq << 7;                   // this thread's k range base

    // Wh slice -> registers (one-time, L2-served)
    float Wreg[128];
#pragma unroll
    for (int i = 0; i < 128; i++)
        Wreg[i] = Wh[(size_t)(kbase + i) * K_N + col];

    lds_h[tid] = 0.f;                            // h_0 = 0

    const int* myrows = rows + g * T_LEN;
    int* myflags = flags + cluster * 4;
    float* hb0 = h_buf + (size_t)cluster * 512;
    float* hb1 = h_buf + (size_t)NCLUSTER * 512 + (size_t)cluster * 512;

    __syncthreads();

    // prefetch x for s = 0
    const int colr = c0 + (tid & 127);
    float xv = 0.f;
    if (tid < 128) {
        int t0 = (dir == 0) ? 0 : (T_LEN - 2);
        xv = P[(size_t)myrows[t0] * K_N + colr];
    }

    for (int s = 0; s < T_LEN; s++) {
        // partial dot over my 128 k's for my column (LDS broadcast reads)
        float a0 = 0.f, a1 = 0.f, a2 = 0.f, a3 = 0.f;
#pragma unroll
        for (int i = 0; i < 128; i += 4) {
            float4 hv = *(const float4*)&lds_h[kbase + i];   // uniform addr -> broadcast
            a0 += hv.x * Wreg[i + 0];
            a1 += hv.y * Wreg[i + 1];
            a2 += hv.z * Wreg[i + 2];
            a3 += hv.w * Wreg[i + 3];
        }
        partial[tid] = (a0 + a1) + (a2 + a3);
        __syncthreads();                                     // A

        if (tid < 128) {
            int chh = tid >> 6, l = tid & 63;
            float sum = partial[(chh * 4 + 0) * 64 + l] + partial[(chh * 4 + 1) * 64 + l]
                      + partial[(chh * 4 + 2) * 64 + l] + partial[(chh * 4 + 3) * 64 + l];
            float z = xv + sum;
            z = fminf(15.f, fmaxf(-15.f, z));
            float e = __expf(2.f * z);
            float h1 = 1.f - 2.f / (e + 1.f);                // tanh(z)

            int tphys = (dir == 0) ? s : ((s == T_LEN - 1) ? (T_LEN - 1) : (T_LEN - 2 - s));
            __builtin_nontemporal_store(
                h1, &out[(size_t)tphys * (G_N * 1024) + g * 1024 + dir * 512 + colr]);
            if (s == T_LEN - 1)
                __builtin_nontemporal_store(
                    h1, &out[(size_t)T_LEN * (G_N * 1024) + g * 1024 + dir * 512 + colr]);

            float* hb = (s & 1) ? hb1 : hb0;
            STORE_RLX(&hb[colr], h1);                        // sc1: straight to LLC
        }
        if (s == T_LEN - 1) break;
        __syncthreads();                                     // B

        if (tid == 0)
            __hip_atomic_store(&myflags[wgc], s + 1, __ATOMIC_RELEASE, __HIP_MEMORY_SCOPE_AGENT);

        // prefetch next x while waiting (P/rows immutable -> stale reads fine)
        if (tid < 128) {
            int sn = s + 1;
            int tn = (dir == 0) ? sn : ((sn == T_LEN - 1) ? (T_LEN - 1) : (T_LEN - 2 - sn));
            xv = P[(size_t)myrows[tn] * K_N + colr];
        }

        // parallel poll: lane i watches flag i (relaxed sc1 loads, no cache inv)
        if (tid < 4) {
            const int target = s + 1;
            while (LOAD_RLX(&myflags[tid]) < target) { }
        }
        __builtin_amdgcn_fence(__ATOMIC_ACQUIRE, "workgroup");  // compiler ordering, no cache ops
        __syncthreads();                                     // C
        {
            const float* hb = (s & 1) ? hb1 : hb0;
            lds_h[tid] = LOAD_RLX(&hb[tid]);                 // sc1: fresh from LLC
        }
        __syncthreads();                                     // D
    }
}

extern "C" void kernel_launch(void* const* d_in, const int* in_sizes, int n_in,
                              void* d_out, int out_size, void* d_ws, size_t ws_size,
                              hipStream_t stream) {
    const float* seq   = (const float*)d_in[0];
    const int*   perms = (const int*)d_in[1];
    const float* We    = (const float*)d_in[2];
    const float* Wx    = (const float*)d_in[3];
    const float* Wh    = (const float*)d_in[4];
    const float* b     = (const float*)d_in[5];
    float* out = (float*)d_out;
    char* ws = (char*)d_ws;

    int*   flags  = (int*)(ws + FLAGS_OFF);
    int*   tokens = (int*)(ws + TOK_OFF);
    int*   rows   = (int*)(ws + ROWS_OFF);
    float* hbuf   = (float*)(ws + HBUF_OFF);
    float* P      = (float*)(ws + P_OFF);

    (void)hipMemsetAsync(flags, 0, NCLUSTER * 4 * sizeof(int), stream);
    tok_kernel<<<512, 256, 0, stream>>>(seq, tokens);
    rows_kernel<<<(G_N * T_LEN + 255) / 256, 256, 0, stream>>>(tokens, perms, rows);
    pgemm_kernel<<<256, 256, 0, stream>>>(We, Wx, b, P);
    rnn_kernel<<<NBLK, 512, 0, stream>>>(P, Wh, rows, hbuf, flags, out);
}